// Round 1
// baseline (157.725 us; speedup 1.0000x reference)
//
#include <hip/hip_runtime.h>

// Problem constants (from reference)
#define N_ATOMS   500000
#define N_ALT     4
#define NB        2      // N_BATCH
#define NC        4      // N_CHAIN
#define NR        50000  // N_RES
#define SG_HASH   16
#define TEMP      298.0f

// Output layout (flat float32):
//   [0, 1600000)            residueEnergy (2,4,50000,4)
//   [1600000, 3600000)      atomEnergy    (500000,4)
//   [3600000, 3600000+P)    sulfur        (P,) as 0.0/1.0
#define RESE_SIZE  (NB * NC * NR * N_ALT)   // 1,600,000
#define ATOME_SIZE (N_ATOMS * N_ALT)        // 2,000,000

__device__ __forceinline__ void heavy_pair(
    int p0, int p1,
    const float* __restrict__ coords,
    const int*   __restrict__ adesc,
    const int*   __restrict__ altmask,
    float* __restrict__ resE,
    float* __restrict__ atomE)
{
    // descriptor rows: [batch, chain, resnum, at_name]
    int4 d0 = *reinterpret_cast<const int4*>(adesc + (size_t)p0 * 4);
    int4 d1 = *reinterpret_cast<const int4*>(adesc + (size_t)p1 * 4);

    float dx = coords[(size_t)p0 * 3 + 0] - coords[(size_t)p1 * 3 + 0] + 1e-6f;
    float dy = coords[(size_t)p0 * 3 + 1] - coords[(size_t)p1 * 3 + 1] + 1e-6f;
    float dz = coords[(size_t)p0 * 3 + 2] - coords[(size_t)p1 * 3 + 2] + 1e-6f;
    float dist = sqrtf(dx * dx + dy * dy + dz * dz);

    float rd = fabsf((float)(d0.z - d1.z));      // sulfur => rd >= 1, log safe
    float energy = -0.001f * TEMP * (2.1f + 2.9823825f * logf(rd))
                 + 5.0f * fabsf(dist - 2.04f);
    float netE = 0.5f * energy;

    int4 m0 = *reinterpret_cast<const int4*>(altmask + (size_t)p0 * 4);
    int4 m1 = *reinterpret_cast<const int4*>(altmask + (size_t)p1 * 4);

    int f0 = ((d0.x * NC + d0.y) * NR + d0.z) * N_ALT;   // residue row base
    int f1 = ((d1.x * NC + d1.y) * NR + d1.z) * N_ALT;

    const int* m0p = &m0.x;
    const int* m1p = &m1.x;
#pragma unroll
    for (int a = 0; a < N_ALT; ++a) {
        if (m0p[a] & m1p[a]) {
            atomicAdd(atomE + (size_t)p0 * N_ALT + a, netE);
            atomicAdd(atomE + (size_t)p1 * N_ALT + a, netE);
            atomicAdd(resE + f0 + a, netE);
            atomicAdd(resE + f1 + a, netE);
        }
    }
}

__global__ __launch_bounds__(256) void disulfide_pair_kernel(
    const float* __restrict__ coords,
    const int*   __restrict__ adesc,    // (N,4)
    const int*   __restrict__ pairs,    // (P,2)
    const int*   __restrict__ altmask,  // (N,4) 0/1
    float* __restrict__ resE,
    float* __restrict__ atomE,
    float* __restrict__ sulfur,
    int P)
{
    int t  = blockIdx.x * blockDim.x + threadIdx.x;
    int i0 = t * 2;                       // two pairs per thread
    if (i0 >= P) return;

    // 16B coalesced load of two pairs: (x,y) = pair i0, (z,w) = pair i0+1
    int4 pp = *reinterpret_cast<const int4*>(pairs + (size_t)i0 * 2);

    int an0 = adesc[(size_t)pp.x * 4 + 3];
    int an1 = adesc[(size_t)pp.y * 4 + 3];
    int an2 = adesc[(size_t)pp.z * 4 + 3];
    int an3 = adesc[(size_t)pp.w * 4 + 3];

    bool s0 = (an0 == SG_HASH) && (an1 == SG_HASH);
    bool s1 = (an2 == SG_HASH) && (an3 == SG_HASH);

    float2 sv = make_float2(s0 ? 1.0f : 0.0f, s1 ? 1.0f : 0.0f);
    *reinterpret_cast<float2*>(sulfur + i0) = sv;

    if (s0) heavy_pair(pp.x, pp.y, coords, adesc, altmask, resE, atomE);
    if (s1) heavy_pair(pp.z, pp.w, coords, adesc, altmask, resE, atomE);
}

extern "C" void kernel_launch(void* const* d_in, const int* in_sizes, int n_in,
                              void* d_out, int out_size, void* d_ws, size_t ws_size,
                              hipStream_t stream) {
    const float* coords  = (const float*)d_in[0];
    const int*   adesc   = (const int*)d_in[1];
    // d_in[2] = atom_number (unused: identical to arange)
    const int*   pairs   = (const int*)d_in[3];
    const int*   altmask = (const int*)d_in[4];
    // d_in[5] = partners (unused), d_in[6] = facc (unused)

    const int P = in_sizes[3] / 2;   // 8,000,000

    float* out    = (float*)d_out;
    float* resE   = out;
    float* atomE  = out + RESE_SIZE;
    float* sulfur = out + RESE_SIZE + ATOME_SIZE;

    // Zero the accumulated outputs every call (atomics below; sulfur region is
    // fully overwritten so no need to clear it).
    hipMemsetAsync(d_out, 0, (size_t)(RESE_SIZE + ATOME_SIZE) * sizeof(float), stream);

    const int threads = 256;
    const int work    = P / 2;                       // 2 pairs per thread
    const int blocks  = (work + threads - 1) / threads;
    disulfide_pair_kernel<<<blocks, threads, 0, stream>>>(
        coords, adesc, pairs, altmask, resE, atomE, sulfur, P);
}

// Round 2
// 48.495 us; speedup vs baseline: 3.2524x; 3.2524x over previous
//
#include <hip/hip_runtime.h>

// Problem constants (from reference)
#define N_ATOMS   500000
#define N_ALT     4
#define NB        2      // N_BATCH
#define NC        4      // N_CHAIN
#define NR        50000  // N_RES
#define SG_HASH   16
#define TEMP      298.0f

// Output layout (flat float32):
//   [0, 1600000)            residueEnergy (2,4,50000,4)
//   [1600000, 3600000)      atomEnergy    (500000,4)
//   [3600000, 3600000+P)    sulfur        (P,) as 0.0/1.0
#define RESE_SIZE  (NB * NC * NR * N_ALT)   // 1,600,000
#define ATOME_SIZE (N_ATOMS * N_ALT)        // 2,000,000

#define MASK_WORDS ((N_ATOMS + 63) / 64)    // 7813 u64 words = 62.5 KB

// ---------------------------------------------------------------------------
// Kernel A: build packed SG bitmask (1 bit per atom). One thread per atom,
// one u64 word per wave via __ballot. 8 MB sequential-ish read, 62.5 KB write.
// ---------------------------------------------------------------------------
__global__ __launch_bounds__(256) void build_sg_mask(
    const int* __restrict__ adesc,          // (N,4)
    unsigned long long* __restrict__ mask)  // (MASK_WORDS,)
{
    int i = blockIdx.x * blockDim.x + threadIdx.x;
    bool s = false;
    if (i < N_ATOMS) s = (adesc[(size_t)i * 4 + 3] == SG_HASH);
    unsigned long long b = __ballot(s);
    if ((threadIdx.x & 63) == 0) mask[i >> 6] = b;
}

__device__ __forceinline__ bool probe(const unsigned long long* __restrict__ m, int idx) {
    return (m[idx >> 6] >> (idx & 63)) & 1ULL;
}

// ---------------------------------------------------------------------------
// Cold path: full energy + scatter for a sulfur pair (~0.1% of pairs).
// ---------------------------------------------------------------------------
__device__ __forceinline__ void heavy_pair(
    int p0, int p1,
    const float* __restrict__ coords,
    const int*   __restrict__ adesc,
    const int*   __restrict__ altmask,
    float* __restrict__ resE,
    float* __restrict__ atomE)
{
    // descriptor rows: [batch, chain, resnum, at_name]
    int4 d0 = *reinterpret_cast<const int4*>(adesc + (size_t)p0 * 4);
    int4 d1 = *reinterpret_cast<const int4*>(adesc + (size_t)p1 * 4);

    float dx = coords[(size_t)p0 * 3 + 0] - coords[(size_t)p1 * 3 + 0] + 1e-6f;
    float dy = coords[(size_t)p0 * 3 + 1] - coords[(size_t)p1 * 3 + 1] + 1e-6f;
    float dz = coords[(size_t)p0 * 3 + 2] - coords[(size_t)p1 * 3 + 2] + 1e-6f;
    float dist = sqrtf(dx * dx + dy * dy + dz * dz);

    float rd = fabsf((float)(d0.z - d1.z));      // sulfur => rd >= 1, log safe
    float energy = -0.001f * TEMP * (2.1f + 2.9823825f * logf(rd))
                 + 5.0f * fabsf(dist - 2.04f);
    float netE = 0.5f * energy;

    int4 m0 = *reinterpret_cast<const int4*>(altmask + (size_t)p0 * 4);
    int4 m1 = *reinterpret_cast<const int4*>(altmask + (size_t)p1 * 4);

    int f0 = ((d0.x * NC + d0.y) * NR + d0.z) * N_ALT;   // residue row base
    int f1 = ((d1.x * NC + d1.y) * NR + d1.z) * N_ALT;

    const int* m0p = &m0.x;
    const int* m1p = &m1.x;
#pragma unroll
    for (int a = 0; a < N_ALT; ++a) {
        if (m0p[a] & m1p[a]) {
            atomicAdd(atomE + (size_t)p0 * N_ALT + a, netE);
            atomicAdd(atomE + (size_t)p1 * N_ALT + a, netE);
            atomicAdd(resE + f0 + a, netE);
            atomicAdd(resE + f1 + a, netE);
        }
    }
}

// ---------------------------------------------------------------------------
// Kernel B: 4 pairs per thread. Stream pairs (2x int4), probe the 62.5 KB
// bitmask (L1/L2-resident), write sulfur as float4. Heavy path is rare.
// ---------------------------------------------------------------------------
__global__ __launch_bounds__(256) void disulfide_pair_kernel(
    const float* __restrict__ coords,
    const int*   __restrict__ adesc,    // (N,4)
    const int*   __restrict__ pairs,    // (P,2)
    const int*   __restrict__ altmask,  // (N,4) 0/1
    const unsigned long long* __restrict__ sgmask,
    float* __restrict__ resE,
    float* __restrict__ atomE,
    float* __restrict__ sulfur,
    int P)
{
    int t  = blockIdx.x * blockDim.x + threadIdx.x;
    int i0 = t * 4;                       // four pairs per thread
    if (i0 >= P) return;

    int4 pa = *reinterpret_cast<const int4*>(pairs + (size_t)i0 * 2);
    int4 pb = *reinterpret_cast<const int4*>(pairs + (size_t)i0 * 2 + 4);

    bool s0 = probe(sgmask, pa.x) && probe(sgmask, pa.y);
    bool s1 = probe(sgmask, pa.z) && probe(sgmask, pa.w);
    bool s2 = probe(sgmask, pb.x) && probe(sgmask, pb.y);
    bool s3 = probe(sgmask, pb.z) && probe(sgmask, pb.w);

    float4 sv = make_float4(s0 ? 1.0f : 0.0f, s1 ? 1.0f : 0.0f,
                            s2 ? 1.0f : 0.0f, s3 ? 1.0f : 0.0f);
    *reinterpret_cast<float4*>(sulfur + i0) = sv;

    if (s0) heavy_pair(pa.x, pa.y, coords, adesc, altmask, resE, atomE);
    if (s1) heavy_pair(pa.z, pa.w, coords, adesc, altmask, resE, atomE);
    if (s2) heavy_pair(pb.x, pb.y, coords, adesc, altmask, resE, atomE);
    if (s3) heavy_pair(pb.z, pb.w, coords, adesc, altmask, resE, atomE);
}

extern "C" void kernel_launch(void* const* d_in, const int* in_sizes, int n_in,
                              void* d_out, int out_size, void* d_ws, size_t ws_size,
                              hipStream_t stream) {
    const float* coords  = (const float*)d_in[0];
    const int*   adesc   = (const int*)d_in[1];
    // d_in[2] = atom_number (unused: identical to arange)
    const int*   pairs   = (const int*)d_in[3];
    const int*   altmask = (const int*)d_in[4];
    // d_in[5] = partners (unused), d_in[6] = facc (unused)

    const int P = in_sizes[3] / 2;   // 8,000,000

    float* out    = (float*)d_out;
    float* resE   = out;
    float* atomE  = out + RESE_SIZE;
    float* sulfur = out + RESE_SIZE + ATOME_SIZE;

    unsigned long long* sgmask = (unsigned long long*)d_ws;   // 62.5 KB

    // Zero the accumulated outputs every call (atomics below; sulfur region is
    // fully overwritten so no need to clear it).
    hipMemsetAsync(d_out, 0, (size_t)(RESE_SIZE + ATOME_SIZE) * sizeof(float), stream);

    // Kernel A: build the SG bitmask.
    {
        const int threads = 256;
        const int blocks  = (N_ATOMS + threads - 1) / threads;
        build_sg_mask<<<blocks, threads, 0, stream>>>(adesc, sgmask);
    }

    // Kernel B: pair streaming.
    {
        const int threads = 256;
        const int work    = (P + 3) / 4;                 // 4 pairs per thread
        const int blocks  = (work + threads - 1) / threads;
        disulfide_pair_kernel<<<blocks, threads, 0, stream>>>(
            coords, adesc, pairs, altmask, sgmask, resE, atomE, sulfur, P);
    }
}

// Round 3
// 32.600 us; speedup vs baseline: 4.8382x; 1.4876x over previous
//
#include <hip/hip_runtime.h>

// Problem constants (from reference)
#define N_ATOMS   500000
#define N_ALT     4
#define NB        2      // N_BATCH
#define NC        4      // N_CHAIN
#define NR        50000  // N_RES
#define SG_HASH   16
#define TEMP      298.0f

// Output layout (flat float32):
//   [0, 1600000)            residueEnergy (2,4,50000,4)
//   [1600000, 3600000)      atomEnergy    (500000,4)
//   [3600000, 3600000+P)    sulfur        (P,) as 0.0/1.0
#define RESE_SIZE  (NB * NC * NR * N_ALT)   // 1,600,000
#define ATOME_SIZE (N_ATOMS * N_ALT)        // 2,000,000

#define MASK_W64   ((N_ATOMS + 63) / 64)    // 7813 u64 = 62,504 B
#define MASK_W32   (MASK_W64 * 2)           // 15626 u32

// ---------------------------------------------------------------------------
// Kernel A: build packed SG bitmask (1 bit per atom) via __ballot.
// ---------------------------------------------------------------------------
__global__ __launch_bounds__(256) void build_sg_mask(
    const int* __restrict__ adesc,          // (N,4)
    unsigned long long* __restrict__ mask)  // (MASK_W64,)
{
    int i = blockIdx.x * blockDim.x + threadIdx.x;
    bool s = false;
    if (i < N_ATOMS) s = (adesc[(size_t)i * 4 + 3] == SG_HASH);
    unsigned long long b = __ballot(s);
    if ((threadIdx.x & 63) == 0) mask[i >> 6] = b;
}

// ---------------------------------------------------------------------------
// Cold path: full energy + scatter for a sulfur pair (~0.1% of pairs).
// ---------------------------------------------------------------------------
__device__ __forceinline__ void heavy_pair(
    int p0, int p1,
    const float* __restrict__ coords,
    const int*   __restrict__ adesc,
    const int*   __restrict__ altmask,
    float* __restrict__ resE,
    float* __restrict__ atomE)
{
    int4 d0 = *reinterpret_cast<const int4*>(adesc + (size_t)p0 * 4);
    int4 d1 = *reinterpret_cast<const int4*>(adesc + (size_t)p1 * 4);

    float dx = coords[(size_t)p0 * 3 + 0] - coords[(size_t)p1 * 3 + 0] + 1e-6f;
    float dy = coords[(size_t)p0 * 3 + 1] - coords[(size_t)p1 * 3 + 1] + 1e-6f;
    float dz = coords[(size_t)p0 * 3 + 2] - coords[(size_t)p1 * 3 + 2] + 1e-6f;
    float dist = sqrtf(dx * dx + dy * dy + dz * dz);

    float rd = fabsf((float)(d0.z - d1.z));      // sulfur => rd >= 1, log safe
    float energy = -0.001f * TEMP * (2.1f + 2.9823825f * logf(rd))
                 + 5.0f * fabsf(dist - 2.04f);
    float netE = 0.5f * energy;

    int4 m0 = *reinterpret_cast<const int4*>(altmask + (size_t)p0 * 4);
    int4 m1 = *reinterpret_cast<const int4*>(altmask + (size_t)p1 * 4);

    int f0 = ((d0.x * NC + d0.y) * NR + d0.z) * N_ALT;
    int f1 = ((d1.x * NC + d1.y) * NR + d1.z) * N_ALT;

    const int* m0p = &m0.x;
    const int* m1p = &m1.x;
#pragma unroll
    for (int a = 0; a < N_ALT; ++a) {
        if (m0p[a] & m1p[a]) {
            atomicAdd(atomE + (size_t)p0 * N_ALT + a, netE);
            atomicAdd(atomE + (size_t)p1 * N_ALT + a, netE);
            atomicAdd(resE + f0 + a, netE);
            atomicAdd(resE + f1 + a, netE);
        }
    }
}

// ---------------------------------------------------------------------------
// Kernel B: broadcast the 62.5 KB SG bitmask into LDS, then grid-stride over
// pairs, 4 pairs/thread/iter. Probes hit LDS (~6 cyc) instead of L2 (~200).
// 1024-thread blocks, 62.5 KB LDS -> 2 blocks/CU = 32 waves/CU (100% occ).
// ---------------------------------------------------------------------------
__global__ __launch_bounds__(1024) void disulfide_pair_kernel(
    const float* __restrict__ coords,
    const int*   __restrict__ adesc,    // (N,4)
    const int*   __restrict__ pairs,    // (P,2)
    const int*   __restrict__ altmask,  // (N,4) 0/1
    const unsigned int* __restrict__ sgmask32,
    float* __restrict__ resE,
    float* __restrict__ atomE,
    float* __restrict__ sulfur,
    int P)
{
    __shared__ unsigned int lmask[MASK_W32];   // 62,504 B

    for (int w = threadIdx.x; w < MASK_W32; w += 1024)
        lmask[w] = sgmask32[w];
    __syncthreads();

    const int tid    = blockIdx.x * 1024 + threadIdx.x;
    const int stride = gridDim.x * 1024 * 4;

    for (int i0 = tid * 4; i0 < P; i0 += stride) {
        int4 pa = *reinterpret_cast<const int4*>(pairs + (size_t)i0 * 2);
        int4 pb = *reinterpret_cast<const int4*>(pairs + (size_t)i0 * 2 + 4);

        // LDS probes: bit (idx&31) of u32 word (idx>>5)
        unsigned m;
        m = (lmask[pa.x >> 5] >> (pa.x & 31)) & (lmask[pa.y >> 5] >> (pa.y & 31));
        bool s0 = m & 1u;
        m = (lmask[pa.z >> 5] >> (pa.z & 31)) & (lmask[pa.w >> 5] >> (pa.w & 31));
        bool s1 = m & 1u;
        m = (lmask[pb.x >> 5] >> (pb.x & 31)) & (lmask[pb.y >> 5] >> (pb.y & 31));
        bool s2 = m & 1u;
        m = (lmask[pb.z >> 5] >> (pb.z & 31)) & (lmask[pb.w >> 5] >> (pb.w & 31));
        bool s3 = m & 1u;

        float4 sv = make_float4(s0 ? 1.0f : 0.0f, s1 ? 1.0f : 0.0f,
                                s2 ? 1.0f : 0.0f, s3 ? 1.0f : 0.0f);
        *reinterpret_cast<float4*>(sulfur + i0) = sv;

        if (s0) heavy_pair(pa.x, pa.y, coords, adesc, altmask, resE, atomE);
        if (s1) heavy_pair(pa.z, pa.w, coords, adesc, altmask, resE, atomE);
        if (s2) heavy_pair(pb.x, pb.y, coords, adesc, altmask, resE, atomE);
        if (s3) heavy_pair(pb.z, pb.w, coords, adesc, altmask, resE, atomE);
    }
}

extern "C" void kernel_launch(void* const* d_in, const int* in_sizes, int n_in,
                              void* d_out, int out_size, void* d_ws, size_t ws_size,
                              hipStream_t stream) {
    const float* coords  = (const float*)d_in[0];
    const int*   adesc   = (const int*)d_in[1];
    // d_in[2] = atom_number (unused)
    const int*   pairs   = (const int*)d_in[3];
    const int*   altmask = (const int*)d_in[4];
    // d_in[5] = partners (unused), d_in[6] = facc (unused)

    const int P = in_sizes[3] / 2;   // 8,000,000

    float* out    = (float*)d_out;
    float* resE   = out;
    float* atomE  = out + RESE_SIZE;
    float* sulfur = out + RESE_SIZE + ATOME_SIZE;

    unsigned long long* sgmask = (unsigned long long*)d_ws;   // 62.5 KB

    // Zero accumulated outputs every call (sulfur region fully overwritten).
    hipMemsetAsync(d_out, 0, (size_t)(RESE_SIZE + ATOME_SIZE) * sizeof(float), stream);

    // Kernel A: build the SG bitmask.
    {
        const int threads = 256;
        const int blocks  = (N_ATOMS + threads - 1) / threads;
        build_sg_mask<<<blocks, threads, 0, stream>>>(adesc, sgmask);
    }

    // Kernel B: pair streaming with LDS-resident bitmask.
    {
        const int threads = 1024;
        const int blocks  = 512;     // 2 resident blocks/CU on 256 CUs
        disulfide_pair_kernel<<<blocks, threads, 0, stream>>>(
            coords, adesc, pairs, altmask, (const unsigned int*)sgmask,
            resE, atomE, sulfur, P);
    }
}